// Round 8
// baseline (453.459 us; speedup 1.0000x reference)
//
#include <hip/hip_runtime.h>

typedef __bf16 bf16x8 __attribute__((ext_vector_type(8)));
typedef float f32x16 __attribute__((ext_vector_type(16)));
typedef unsigned short us8 __attribute__((ext_vector_type(8)));

#define AS1 __attribute__((address_space(1)))
#define AS3 __attribute__((address_space(3)))

__device__ __forceinline__ unsigned short f2bf(float x) {
  unsigned int u = __float_as_uint(x);
  u += 0x7fffu + ((u >> 16) & 1u);   // RNE
  return (unsigned short)(u >> 16);
}
__device__ __forceinline__ float bf2f(unsigned short u) {
  return __uint_as_float(((unsigned int)u) << 16);
}
__device__ __forceinline__ void async_copy16(const void* g, void* l) {
  __builtin_amdgcn_global_load_lds((AS1 void*)(g), (AS3 void*)(l), 16, 0, 0);
}

#define BARRIER() asm volatile("s_barrier" ::: "memory")
#define WAITV(n) asm volatile("s_waitcnt vmcnt(" #n ")" ::: "memory")

// ---- device-scope grid barrier (persistent kernel; 256 blocks, all resident:
// grid == CU count, 128 KiB LDS -> 1 block/CU, so every block is dispatched before
// any completes). __syncthreads drains each thread's vmem (compiler emits
// s_waitcnt vmcnt(0) before s_barrier); tid0's RELEASE fetch_add at AGENT scope
// writes back the XCD's L2 (cross-XCD coherence, G16); ACQUIRE spin-load
// invalidates stale L1/L2 before post-barrier reads. Counters zeroed per-replay
// by hipMemsetAsync in kernel_launch.
__device__ __forceinline__ void gsync(unsigned* bar, int slot) {
  __syncthreads();
  if (threadIdx.x == 0) {
    __hip_atomic_fetch_add(&bar[slot], 1u, __ATOMIC_RELEASE, __HIP_MEMORY_SCOPE_AGENT);
    while (__hip_atomic_load(&bar[slot], __ATOMIC_ACQUIRE, __HIP_MEMORY_SCOPE_AGENT) < 256u)
      __builtin_amdgcn_s_sleep(2);
    __threadfence();
  }
  __syncthreads();
}

// ---------------- GEMM stage: C[M,N] = A[M,K] * B[N,K]^T, bf16 in/out -------------
// r8 body VERBATIM (best measured; r9-r13 variants all regressed). 256x256 tile,
// BK=64, 8 waves (2Mx4N), dbuf 128 KiB LDS, 4-phase K-tile with counted vmcnt.
template <bool STATS>
__device__ __forceinline__ void gemm_body(int f, int NBX, int NBY,
                                          const unsigned short* __restrict__ A,
                                          const unsigned short* __restrict__ B,
                                          unsigned short* __restrict__ C, int K,
                                          int lda, int ldb, int ldc, long koff,
                                          float* __restrict__ P,
                                          unsigned short* lAb, unsigned short* lBb) {
  const int tid = threadIdx.x;
  const int wave = tid >> 6;
  const int lane = tid & 63;
  const int l31 = lane & 31;
  const int khi = lane >> 5;
  const int r7 = l31 & 7;
  const int wrh = wave >> 2;
  const int wcn = wave & 3;

  // XCD-aware bijective remap (f&7 = XCD)
  const int xcd = f & 7;
  const int fi = f >> 3;
  const int nblk = fi % NBX;
  const int mblk = fi / NBX + (NBY >> 3) * xcd;
  const long m0 = (long)mblk * 256;
  const long n0 = (long)nblk * 256;
  const int NT = K >> 6;

  const int rsub = lane >> 3;
  const int qg = ((lane & 7) ^ rsub) * 8;
  const unsigned short* gAq0 = A + (m0 +       8 * wave + rsub) * (long)lda + koff + qg;
  const unsigned short* gAq1 = A + (m0 +  64 + 8 * wave + rsub) * (long)lda + koff + qg;
  const unsigned short* gAq2 = A + (m0 + 128 + 8 * wave + rsub) * (long)lda + koff + qg;
  const unsigned short* gAq3 = A + (m0 + 192 + 8 * wave + rsub) * (long)lda + koff + qg;
  const unsigned short* gB0  = B + (n0 + 32 * wave + rsub) * (long)ldb + koff + qg;
  const unsigned short* gB1  = gB0 +  8 * (long)ldb;
  const unsigned short* gB2  = gB0 + 16 * (long)ldb;
  const unsigned short* gB3  = gB0 + 24 * (long)ldb;
  const int dAq0 = (      8 * wave) * 64;
  const int dAq1 = ( 64 + 8 * wave) * 64;
  const int dAq2 = (128 + 8 * wave) * 64;
  const int dAq3 = (192 + 8 * wave) * 64;
  const int dB0  = (32 * wave) * 64;

  f32x16 acc[4][2];
#pragma unroll
  for (int i = 0; i < 4; ++i)
#pragma unroll
    for (int j = 0; j < 2; ++j) acc[i][j] = (f32x16)(0.f);

#define PH_READS(rh, kh, DOB)                                                        \
  bf16x8 af[2][2];                                                                   \
  _Pragma("unroll") for (int i = 0; i < 2; ++i) {                                    \
    _Pragma("unroll") for (int ks = 0; ks < 2; ++ks) {                               \
      af[i][ks] = *(const bf16x8*)&lAc[(wrh * 128 + (rh) * 64 + i * 32 + l31) * 64 + \
                                       ((((kh) * 2 + ks) * 2 + khi) ^ r7) * 8];      \
    }                                                                                \
  }                                                                                  \
  if (DOB) {                                                                         \
    _Pragma("unroll") for (int j = 0; j < 2; ++j) {                                  \
      _Pragma("unroll") for (int ks = 0; ks < 2; ++ks) {                             \
        bf[j][ks] = *(const bf16x8*)&lBc[(wcn * 64 + j * 32 + l31) * 64 +            \
                                         ((((kh) * 2 + ks) * 2 + khi) ^ r7) * 8];    \
      }                                                                              \
    }                                                                                \
  }

#define PH_MFMA(rh)                                                                 \
  __builtin_amdgcn_s_setprio(1);                                                    \
  _Pragma("unroll") for (int ks = 0; ks < 2; ++ks) {                                 \
    _Pragma("unroll") for (int i = 0; i < 2; ++i) {                                  \
      _Pragma("unroll") for (int j = 0; j < 2; ++j) {                                \
        acc[(rh) * 2 + i][j] = __builtin_amdgcn_mfma_f32_32x32x16_bf16(              \
            af[i][ks], bf[j][ks], acc[(rh) * 2 + i][j], 0, 0, 0);                    \
      }                                                                              \
    }                                                                                \
  }                                                                                  \
  __builtin_amdgcn_s_setprio(0);

  {
    unsigned short* lAn = lAb;
    unsigned short* lBn = lBb;
    async_copy16(gAq0, lAn + dAq0);
    async_copy16(gAq2, lAn + dAq2);
    async_copy16(gB0,  lBn + dB0);
    async_copy16(gB1,  lBn + dB0 + 8 * 64);
    async_copy16(gB2,  lBn + dB0 + 16 * 64);
    async_copy16(gB3,  lBn + dB0 + 24 * 64);
    async_copy16(gAq1, lAn + dAq1);
    async_copy16(gAq3, lAn + dAq3);
    WAITV(2);
    BARRIER();
  }

  for (int t = 0; t < NT - 1; ++t) {
    const unsigned short* lAc = lAb + (t & 1) * 16384;
    const unsigned short* lBc = lBb + (t & 1) * 16384;
    unsigned short* lAn = lAb + ((t + 1) & 1) * 16384;
    unsigned short* lBn = lBb + ((t + 1) & 1) * 16384;
    const long kk = (long)(t + 1) * 64;
    bf16x8 bf[2][2];
    {
      PH_READS(0, 0, 1)
      async_copy16(gAq0 + kk, lAn + dAq0);
      async_copy16(gAq2 + kk, lAn + dAq2);
      BARRIER();
      PH_MFMA(0)
      WAITV(2);
      BARRIER();
    }
    {
      PH_READS(1, 0, 0)
      async_copy16(gB0 + kk, lBn + dB0);
      async_copy16(gB1 + kk, lBn + dB0 + 8 * 64);
      BARRIER();
      PH_MFMA(1)
      BARRIER();
    }
    {
      PH_READS(0, 1, 1)
      async_copy16(gB2 + kk, lBn + dB0 + 16 * 64);
      async_copy16(gB3 + kk, lBn + dB0 + 24 * 64);
      BARRIER();
      PH_MFMA(0)
      BARRIER();
    }
    {
      PH_READS(1, 1, 0)
      async_copy16(gAq1 + kk, lAn + dAq1);
      async_copy16(gAq3 + kk, lAn + dAq3);
      BARRIER();
      PH_MFMA(1)
      WAITV(2);
      BARRIER();
    }
  }

  {
    const unsigned short* lAc = lAb + ((NT - 1) & 1) * 16384;
    const unsigned short* lBc = lBb + ((NT - 1) & 1) * 16384;
    bf16x8 bf[2][2];
    { PH_READS(0, 0, 1) BARRIER(); PH_MFMA(0) WAITV(0); BARRIER(); }
    { PH_READS(1, 0, 0) BARRIER(); PH_MFMA(1) BARRIER(); }
    { PH_READS(0, 1, 1) BARRIER(); PH_MFMA(0) BARRIER(); }
    { PH_READS(1, 1, 0) BARRIER(); PH_MFMA(1) BARRIER(); }
  }
#undef PH_READS
#undef PH_MFMA

  const int rbase = 4 * khi;
  const long crow0 = m0 + wrh * 128;
  const long ccol0 = n0 + wcn * 64;
#pragma unroll
  for (int ig = 0; ig < 4; ++ig)
#pragma unroll
    for (int j = 0; j < 2; ++j) {
      long col = ccol0 + j * 32 + l31;
#pragma unroll
      for (int reg = 0; reg < 16; ++reg) {
        long row = crow0 + ig * 32 + (reg & 3) + 8 * (reg >> 2) + rbase;
        C[row * (long)ldc + col] = f2bf(acc[ig][j][reg]);
      }
    }

  if (STATS) {
    float* sred = (float*)lAb;         // lA[0]; last tile read lA[1] (NT even)
    sred[tid] = 0.f;                   // sum[0..255] | sumsq[256..511]
    __syncthreads();
#pragma unroll
    for (int j = 0; j < 2; ++j) {
      float s = 0.f, s2 = 0.f;
#pragma unroll
      for (int ig = 0; ig < 4; ++ig)
#pragma unroll
        for (int reg = 0; reg < 16; ++reg) {
          float v = acc[ig][j][reg];
          s += v;
          s2 = fmaf(v, v, s2);
        }
      int cl = wcn * 64 + j * 32 + l31;
      atomicAdd(&sred[cl], s);
      atomicAdd(&sred[256 + cl], s2);
    }
    __syncthreads();
    if (tid < 256) atomicAdd(&P[n0 + tid], sred[tid]);
    else           atomicAdd(&P[2048 + n0 + tid - 256], sred[tid]);
  }
}

// ---- BN finalize (per-block LDS table, 4 rsqrtf/thread) + BN-apply + relu +
// row-norm + hyperbolic factor. 32 rows/block, wave-per-row x4. Same op order as
// the verified k_bnfin+k_fuse pair -> bit-identical results.
template <bool STAGE2>
__device__ __forceinline__ void bnfuse_body(int b, const float* __restrict__ P,
                                            const float* __restrict__ g,
                                            const float* __restrict__ be,
                                            const unsigned short* __restrict__ Zb,
                                            unsigned short* __restrict__ Ab,
                                            float* scsh) {
  const int tid = threadIdx.x, wave = tid >> 6, lane = tid & 63;
  {
    float4 s = ((const float4*)P)[tid];
    float4 q = ((const float4*)P)[512 + tid];
    float4 gg = ((const float4*)g)[tid];
    float4 bb = ((const float4*)be)[tid];
    float sm[4] = {s.x, s.y, s.z, s.w}, sq[4] = {q.x, q.y, q.z, q.w};
    float gv[4] = {gg.x, gg.y, gg.z, gg.w}, bv[4] = {bb.x, bb.y, bb.z, bb.w};
#pragma unroll
    for (int k = 0; k < 4; ++k) {
      float mean = sm[k] * (1.f / 8192.f);
      float var = sq[k] * (1.f / 8192.f) - mean * mean;
      float a = gv[k] * rsqrtf(var + 1e-5f);
      scsh[tid * 4 + k] = a;
      scsh[2048 + tid * 4 + k] = bv[k] - mean * a;
    }
  }
  __syncthreads();

  float sc[32], sh[32];
#pragma unroll
  for (int c = 0; c < 4; ++c) {
    int cb = (lane + 64 * c) * 8;
    float4 a0 = *(const float4*)&scsh[cb],        a1 = *(const float4*)&scsh[cb + 4];
    float4 h0 = *(const float4*)&scsh[2048 + cb], h1 = *(const float4*)&scsh[2048 + cb + 4];
    sc[c * 8 + 0] = a0.x; sc[c * 8 + 1] = a0.y; sc[c * 8 + 2] = a0.z; sc[c * 8 + 3] = a0.w;
    sc[c * 8 + 4] = a1.x; sc[c * 8 + 5] = a1.y; sc[c * 8 + 6] = a1.z; sc[c * 8 + 7] = a1.w;
    sh[c * 8 + 0] = h0.x; sh[c * 8 + 1] = h0.y; sh[c * 8 + 2] = h0.z; sh[c * 8 + 3] = h0.w;
    sh[c * 8 + 4] = h1.x; sh[c * 8 + 5] = h1.y; sh[c * 8 + 6] = h1.z; sh[c * 8 + 7] = h1.w;
  }

  const float rsc = 0.31622776601683794f;  // sqrt(0.1)
#pragma unroll 1
  for (int r = 0; r < 4; ++r) {
    const long row = (long)b * 32 + r * 8 + wave;
    const us8* zr = (const us8*)(Zb + row * 2048);
    float v[32];
    float ss = 0.f;
#pragma unroll
    for (int c = 0; c < 4; ++c) {
      us8 z8 = zr[lane + 64 * c];
#pragma unroll
      for (int j = 0; j < 8; ++j) {
        float xv = fmaxf(fmaf(bf2f(z8[j]), sc[c * 8 + j], sh[c * 8 + j]), 0.f);
        v[c * 8 + j] = xv;
        ss = fmaf(xv, xv, ss);
      }
    }
#pragma unroll
    for (int o = 32; o > 0; o >>= 1) ss += __shfl_xor(ss, o, 64);
    float n2 = ss;

    float fac;
    if (STAGE2) {
      float nn = sqrtf(n2);
      float vn = fmaxf(nn, 1e-8f);
      float tt = rsc * vn;
      float scl = tanhf(tt) / tt;
      float hn = scl * nn;
      float cn = fminf(fmaxf(hn, 1e-8f), 1.0f);
      float z = rsc * cn;
      fac = scl * (atanhf(z) / z);
    } else {
      fac = 0.f;
      if (n2 > 0.f) {
        float n = sqrtf(n2);
        float th = tanhf(rsc * n);
        float s = 0.9f * th / (rsc * n);
        float dn = fmaxf(s * n, 1e-8f);
        float z = rsc * dn;
        fac = -(atanhf(z) / z) * s;
      }
    }
    us8* dr = (us8*)(Ab + row * 2048);
#pragma unroll
    for (int c = 0; c < 4; ++c) {
      us8 o8;
#pragma unroll
      for (int j = 0; j < 8; ++j) o8[j] = f2bf(v[c * 8 + j] * fac);
      dr[lane + 64 * c] = o8;
    }
  }
}

// ---- log_softmax over 1000 cols, 32 rows/block, wave-per-row x4 (vectorized) ----
__device__ __forceinline__ void lsm_body(int b, const unsigned short* __restrict__ Za,
                                         const unsigned short* __restrict__ Zb2,
                                         const float* __restrict__ b3,
                                         float* __restrict__ out) {
  const int tid = threadIdx.x, wave = tid >> 6, lane = tid & 63;
#pragma unroll 1
  for (int r = 0; r < 4; ++r) {
    const long row = (long)b * 32 + r * 8 + wave;
    const us8* za8 = (const us8*)(Za + row * 1024);
    const us8* zb8 = (const us8*)(Zb2 + row * 1024);

    float v[16];
    float mx = -3.4e38f;
#pragma unroll
    for (int c = 0; c < 2; ++c) {
      const bool ok = (c == 0) | (lane < 61);
      if (ok) {
        us8 a8 = za8[c * 64 + lane];
        us8 b8 = zb8[c * 64 + lane];
        const float* bp = b3 + c * 512 + lane * 8;
        float4 bA = *(const float4*)bp;
        float4 bB = *(const float4*)(bp + 4);
        float bb[8] = {bA.x, bA.y, bA.z, bA.w, bB.x, bB.y, bB.z, bB.w};
#pragma unroll
        for (int j = 0; j < 8; ++j) {
          float x = bf2f(a8[j]) + bf2f(b8[j]) + bb[j];
          v[c * 8 + j] = x;
          mx = fmaxf(mx, x);
        }
      } else {
#pragma unroll
        for (int j = 0; j < 8; ++j) v[c * 8 + j] = -3.4e38f;
      }
    }
#pragma unroll
    for (int o = 32; o > 0; o >>= 1) mx = fmaxf(mx, __shfl_xor(mx, o, 64));

    float se = 0.f;
#pragma unroll
    for (int c = 0; c < 2; ++c)
#pragma unroll
      for (int j = 0; j < 8; ++j)
        if ((c == 0) | (lane < 61)) se += expf(v[c * 8 + j] - mx);
#pragma unroll
    for (int o = 32; o > 0; o >>= 1) se += __shfl_xor(se, o, 64);
    float mls = mx + logf(se);

    float* orow = out + row * 1000;
#pragma unroll
    for (int c = 0; c < 2; ++c) {
      if ((c == 0) | (lane < 61)) {
        float4 o0 = {v[c * 8 + 0] - mls, v[c * 8 + 1] - mls, v[c * 8 + 2] - mls, v[c * 8 + 3] - mls};
        float4 o1 = {v[c * 8 + 4] - mls, v[c * 8 + 5] - mls, v[c * 8 + 6] - mls, v[c * 8 + 7] - mls};
        float* op = orow + c * 512 + lane * 8;
        *(float4*)op = o0;
        *(float4*)(op + 4) = o1;
      }
    }
  }
}

// ---- THE mega-kernel: whole network in one launch, grid barriers between stages.
__global__ void __launch_bounds__(512, 2) k_mega(
    const float* __restrict__ x, const float* __restrict__ W1,
    const float* __restrict__ g1, const float* __restrict__ be1,
    const float* __restrict__ W2, const float* __restrict__ g2,
    const float* __restrict__ be2, const float* __restrict__ W3,
    const float* __restrict__ b3,
    unsigned short* __restrict__ Xb, unsigned short* __restrict__ W1b,
    unsigned short* __restrict__ W2b, unsigned short* __restrict__ W3b,
    unsigned short* __restrict__ Zb, unsigned short* __restrict__ Ab,
    unsigned short* __restrict__ Z3a, float* __restrict__ P1,
    float* __restrict__ P2, unsigned* __restrict__ bar,
    float* __restrict__ out) {
  __shared__ __align__(16) unsigned short lA[2][256 * 64];   // 64 KB
  __shared__ __align__(16) unsigned short lB[2][256 * 64];   // 64 KB
  const int b = blockIdx.x;
  const int tid = threadIdx.x;
  unsigned short* Z3b = Zb;   // split-K slice 1 aliases Zb (dead by then)

  // -- stage 0: all f32->bf16 conversions (P/bar zeroed by host memset) --
  {
    const long n1 = 2097152, n2 = 524288, n3 = 1048576;   // x | W1 | W2 | W3(pad)
    long i = (long)b * 512 + tid;
#pragma unroll 1
    for (int it = 0; it < 32; ++it, i += 131072) {
      long j = i;
      const float* s;
      unsigned short* d;
      if (i < n1)              { s = x;  d = Xb; }
      else if ((j -= n1) < n2) { s = W1; d = W1b; }
      else if ((j -= n2) < n3) { s = W2; d = W2b; }
      else {
        j -= n3;                                   // W3 region, 524288 groups
        ushort4 o;
        if ((j >> 9) < 1000) {
          float4 v = ((const float4*)W3)[j];
          o.x = f2bf(v.x); o.y = f2bf(v.y); o.z = f2bf(v.z); o.w = f2bf(v.w);
        } else { o.x = 0; o.y = 0; o.z = 0; o.w = 0; }
        ((ushort4*)W3b)[j] = o;
        continue;
      }
      float4 v = ((const float4*)s)[j];
      ushort4 o;
      o.x = f2bf(v.x); o.y = f2bf(v.y); o.z = f2bf(v.z); o.w = f2bf(v.w);
      ((ushort4*)d)[j] = o;
    }
  }
  gsync(bar, 0);

  // -- stage 1: GEMM1 (8192x2048x1024) + BN stats -> P1 --
  gemm_body<true>(b, 8, 32, Xb, W1b, Zb, 1024, 1024, 1024, 2048, 0, P1,
                  &lA[0][0], &lB[0][0]);
  gsync(bar, 1);

  // -- stage 2: BN finalize + fuse1 --
  bnfuse_body<false>(b, P1, g1, be1, Zb, Ab, (float*)&lA[0][0]);
  gsync(bar, 2);

  // -- stage 3: GEMM2 (8192x2048x2048) + BN stats -> P2 --
  gemm_body<true>(b, 8, 32, Ab, W2b, Zb, 2048, 2048, 2048, 2048, 0, P2,
                  &lA[0][0], &lB[0][0]);
  gsync(bar, 3);

  // -- stage 4: BN finalize + fuse2 (STAGE2 hyperbolic chain) --
  bnfuse_body<true>(b, P2, g2, be2, Zb, Ab, (float*)&lA[0][0]);
  gsync(bar, 4);

  // -- stage 5: GEMM3 (8192x1024x2048), split-K=2 by block half --
  {
    const int z = b >> 7;
    const int f = b & 127;
    gemm_body<false>(f, 4, 32, Ab, W3b, z ? Z3b : Z3a, 1024, 2048, 2048, 1024,
                     (long)z * 1024, nullptr, &lA[0][0], &lB[0][0]);
  }
  gsync(bar, 5);

  // -- stage 6: bias + sum split-K partials + log_softmax --
  lsm_body(b, Z3a, Z3b, b3, out);
}

extern "C" void kernel_launch(void* const* d_in, const int* in_sizes, int n_in,
                              void* d_out, int out_size, void* d_ws, size_t ws_size,
                              hipStream_t stream) {
  (void)in_sizes; (void)n_in; (void)out_size; (void)ws_size;
  const float* x   = (const float*)d_in[0];
  const float* W1  = (const float*)d_in[1];
  // d_in[2] = b1: exactly cancelled by BN (mean absorbs it)
  const float* g1  = (const float*)d_in[3];
  const float* be1 = (const float*)d_in[4];
  const float* W2  = (const float*)d_in[5];
  // d_in[6] = b2: cancelled by BN
  const float* g2  = (const float*)d_in[7];
  const float* be2 = (const float*)d_in[8];
  const float* W3  = (const float*)d_in[9];
  const float* b3  = (const float*)d_in[10];
  float* out = (float*)d_out;

  char* ws = (char*)d_ws;
  size_t off = 0;
  auto alloc = [&](size_t bytes) {
    void* p = ws + off;
    off += (bytes + 255) & ~(size_t)255;
    return p;
  };
  unsigned short* Xb  = (unsigned short*)alloc((size_t)8192 * 1024 * 2);
  unsigned short* W1b = (unsigned short*)alloc((size_t)2048 * 1024 * 2);
  unsigned short* W2b = (unsigned short*)alloc((size_t)2048 * 2048 * 2);
  unsigned short* W3b = (unsigned short*)alloc((size_t)1024 * 2048 * 2);
  unsigned short* Zb  = (unsigned short*)alloc((size_t)8192 * 2048 * 2);
  unsigned short* Ab  = (unsigned short*)alloc((size_t)8192 * 2048 * 2);
  unsigned short* Z3a = (unsigned short*)alloc((size_t)8192 * 1024 * 2);
  float* P            = (float*)alloc((size_t)2 * 4096 * 4 + 256);  // P1|P2|bar
  float* P2 = P + 4096;
  unsigned* bar = (unsigned*)(P + 8192);

  // zero P1, P2, and the 6 grid-barrier counters each replay (graph-capturable)
  hipMemsetAsync(P, 0, (size_t)2 * 4096 * 4 + 256, stream);

  k_mega<<<256, 512, 0, stream>>>(x, W1, g1, be1, W2, g2, be2, W3, b3,
                                  Xb, W1b, W2b, W3b, Zb, Ab, Z3a,
                                  P, P2, bar, out);
}

// Round 9
// 306.365 us; speedup vs baseline: 1.4801x; 1.4801x over previous
//
#include <hip/hip_runtime.h>

typedef __bf16 bf16x8 __attribute__((ext_vector_type(8)));
typedef float f32x16 __attribute__((ext_vector_type(16)));
typedef unsigned short us8 __attribute__((ext_vector_type(8)));

#define AS1 __attribute__((address_space(1)))
#define AS3 __attribute__((address_space(3)))

__device__ __forceinline__ unsigned short f2bf(float x) {
  unsigned int u = __float_as_uint(x);
  u += 0x7fffu + ((u >> 16) & 1u);   // RNE
  return (unsigned short)(u >> 16);
}
__device__ __forceinline__ float bf2f(unsigned short u) {
  return __uint_as_float(((unsigned int)u) << 16);
}
__device__ __forceinline__ void async_copy16(const void* g, void* l) {
  __builtin_amdgcn_global_load_lds((AS1 void*)(g), (AS3 void*)(l), 16, 0, 0);
}

// raw barrier (no compiler-inserted full waitcnt drain) + counted vmem waits.
#define BARRIER() asm volatile("s_barrier" ::: "memory")
#define WAITV(n) asm volatile("s_waitcnt vmcnt(" #n ")" ::: "memory")

// ------------- prep: all f32->bf16 conversions + P zeroing, one launch -------------
__global__ void __launch_bounds__(256) k_prep(const float* __restrict__ x,
                                              const float* __restrict__ W1,
                                              const float* __restrict__ W2,
                                              const float* __restrict__ W3,
                                              unsigned short* __restrict__ Xb,
                                              unsigned short* __restrict__ W1b,
                                              unsigned short* __restrict__ W2b,
                                              unsigned short* __restrict__ W3b,
                                              float* __restrict__ P) {
  const long n1 = 2097152, n2 = 524288, n3 = 1048576, n4 = 524288;
  long i = (long)blockIdx.x * 256 + threadIdx.x;   // float4 group index
  const float* s = nullptr;
  unsigned short* d = nullptr;
  long j = i;
  if (i < n1)                { s = x;  d = Xb; }
  else if ((j -= n1) < n2)   { s = W1; d = W1b; }
  else if ((j -= n2) < n3)   { s = W2; d = W2b; }
  else if ((j -= n3) < n4) {
    // W3: [1000,2048] -> padded [1024,2048], zero rows >= 1000
    ushort4 o;
    if ((j >> 9) < 1000) {
      float4 v = ((const float4*)W3)[j];
      o.x = f2bf(v.x); o.y = f2bf(v.y); o.z = f2bf(v.z); o.w = f2bf(v.w);
    } else { o.x = 0; o.y = 0; o.z = 0; o.w = 0; }
    ((ushort4*)W3b)[j] = o;
    return;
  } else {
    j -= n4;                                        // 0..2047 -> zero P (2 buffers)
    ((float4*)P)[j] = (float4){0.f, 0.f, 0.f, 0.f};
    return;
  }
  float4 v = ((const float4*)s)[j];
  ushort4 o;
  o.x = f2bf(v.x); o.y = f2bf(v.y); o.z = f2bf(v.z); o.w = f2bf(v.w);
  ((ushort4*)d)[j] = o;
}

// ---------------- GEMM: C[M,N] = A[M,K] * B[N,K]^T, bf16 in -----------------------
// r8 body VERBATIM (best measured: 71.5-76 us @ 8192x2048x2048; r9-r13 structural
// variants and the r15 persistent mega-kernel all regressed). 256x256 tile, BK=64,
// 8 waves (2Mx4N), dbuf 128 KiB LDS, 4-phase K-tile with counted vmcnt:
// ph0:{A-q0,A-q2} ph1:{B0,B1} ph2:{B2,B3} ph3:{A-q1,A-q3}; WAITV(2) at end-ph0
// and end-ph3; vmcnt never drains to 0 in the main loop; peeled last tile.
// Known profile: MfmaUtil 38-39%, SQ_LDS_BANK_CONFLICT 6.29M (staging-write
// artifact, 4cyc/ds_read fixed by read geometry - not fixable by swizzle).
template <bool OUTBF16, bool STATS>
__global__ void __launch_bounds__(512, 2) k_gemm(const unsigned short* __restrict__ A,
                                                 const unsigned short* __restrict__ B,
                                                 void* __restrict__ Cout,
                                                 void* __restrict__ Cout2, int K,
                                                 int lda, int ldb, int ldc,
                                                 float* __restrict__ P) {
  __shared__ __align__(16) unsigned short lA[2][256 * 64];   // 64 KB
  __shared__ __align__(16) unsigned short lB[2][256 * 64];   // 64 KB
  const int tid = threadIdx.x;
  const int wave = tid >> 6;
  const int lane = tid & 63;
  const int l31 = lane & 31;
  const int khi = lane >> 5;                      // 0..1
  const int r7 = l31 & 7;                         // fragment row & 7 (swizzle key)
  const int wrh = wave >> 2;                      // 0..1 -> wave row offset *128
  const int wcn = wave & 3;                       // 0..3 -> wave col offset *64

  // XCD-aware bijective remap (f&7 = XCD; each XCD owns a contiguous m-stripe)
  const int f = blockIdx.x + gridDim.x * blockIdx.y;
  const int xcd = f & 7;
  const int fi = f >> 3;
  const int nblk = fi % gridDim.x;
  const int mblk = fi / gridDim.x + (gridDim.y >> 3) * xcd;
  const long m0 = (long)mblk * 256;
  const long n0 = (long)nblk * 256;
  const long koff = (long)blockIdx.z * K;
  const int NT = K >> 6;

  // staging: one global_load_lds issue = 64 lanes x 16B = 8 rows x 64 bf16.
  // lane -> (rsub = lane>>3 row-in-issue, swizzled global chunk (lane&7)^rsub).
  const int rsub = lane >> 3;
  const int qg = ((lane & 7) ^ rsub) * 8;
  const unsigned short* gAq0 = A + (m0 +       8 * wave + rsub) * (long)lda + koff + qg;
  const unsigned short* gAq1 = A + (m0 +  64 + 8 * wave + rsub) * (long)lda + koff + qg;
  const unsigned short* gAq2 = A + (m0 + 128 + 8 * wave + rsub) * (long)lda + koff + qg;
  const unsigned short* gAq3 = A + (m0 + 192 + 8 * wave + rsub) * (long)lda + koff + qg;
  const unsigned short* gB0  = B + (n0 + 32 * wave + rsub) * (long)ldb + koff + qg;
  const unsigned short* gB1  = gB0 +  8 * (long)ldb;
  const unsigned short* gB2  = gB0 + 16 * (long)ldb;
  const unsigned short* gB3  = gB0 + 24 * (long)ldb;
  const int dAq0 = (      8 * wave) * 64;
  const int dAq1 = ( 64 + 8 * wave) * 64;
  const int dAq2 = (128 + 8 * wave) * 64;
  const int dAq3 = (192 + 8 * wave) * 64;
  const int dB0  = (32 * wave) * 64;

  f32x16 acc[4][2];
#pragma unroll
  for (int i = 0; i < 4; ++i)
#pragma unroll
    for (int j = 0; j < 2; ++j) acc[i][j] = (f32x16)(0.f);

// phase helpers: all indices compile-time after unroll (no scratch).
#define PH_READS(rh, kh, DOB)                                                        \
  bf16x8 af[2][2];                                                                   \
  _Pragma("unroll") for (int i = 0; i < 2; ++i) {                                    \
    _Pragma("unroll") for (int ks = 0; ks < 2; ++ks) {                               \
      af[i][ks] = *(const bf16x8*)&lAc[(wrh * 128 + (rh) * 64 + i * 32 + l31) * 64 + \
                                       ((((kh) * 2 + ks) * 2 + khi) ^ r7) * 8];      \
    }                                                                                \
  }                                                                                  \
  if (DOB) {                                                                         \
    _Pragma("unroll") for (int j = 0; j < 2; ++j) {                                  \
      _Pragma("unroll") for (int ks = 0; ks < 2; ++ks) {                             \
        bf[j][ks] = *(const bf16x8*)&lBc[(wcn * 64 + j * 32 + l31) * 64 +            \
                                         ((((kh) * 2 + ks) * 2 + khi) ^ r7) * 8];    \
      }                                                                              \
    }                                                                                \
  }

#define PH_MFMA(rh)                                                                 \
  __builtin_amdgcn_s_setprio(1);                                                    \
  _Pragma("unroll") for (int ks = 0; ks < 2; ++ks) {                                 \
    _Pragma("unroll") for (int i = 0; i < 2; ++i) {                                  \
      _Pragma("unroll") for (int j = 0; j < 2; ++j) {                                \
        acc[(rh) * 2 + i][j] = __builtin_amdgcn_mfma_f32_32x32x16_bf16(              \
            af[i][ks], bf[j][ks], acc[(rh) * 2 + i][j], 0, 0, 0);                    \
      }                                                                              \
    }                                                                                \
  }                                                                                  \
  __builtin_amdgcn_s_setprio(0);

  // prologue: stage tile 0 (6 early, 2 late), land the early set, keep late in flight
  {
    unsigned short* lAn = &lA[0][0];
    unsigned short* lBn = &lB[0][0];
    async_copy16(gAq0, lAn + dAq0);
    async_copy16(gAq2, lAn + dAq2);
    async_copy16(gB0,  lBn + dB0);
    async_copy16(gB1,  lBn + dB0 + 8 * 64);
    async_copy16(gB2,  lBn + dB0 + 16 * 64);
    async_copy16(gB3,  lBn + dB0 + 24 * 64);
    async_copy16(gAq1, lAn + dAq1);
    async_copy16(gAq3, lAn + dAq3);
    WAITV(2);
    BARRIER();
  }

  for (int t = 0; t < NT - 1; ++t) {
    const unsigned short* lAc = &lA[t & 1][0];
    const unsigned short* lBc = &lB[t & 1][0];
    unsigned short* lAn = &lA[(t + 1) & 1][0];
    unsigned short* lBn = &lB[(t + 1) & 1][0];
    const long kk = (long)(t + 1) * 64;
    bf16x8 bf[2][2];
    { // ph0: (rh0, kh0) — needs A-q0/q2 + B (the "early" set of tile t)
      PH_READS(0, 0, 1)
      async_copy16(gAq0 + kk, lAn + dAq0);
      async_copy16(gAq2 + kk, lAn + dAq2);
      BARRIER();
      PH_MFMA(0)
      WAITV(2);        // lands A-q1/q3 of tile t (issued at t-1 ph3)
      BARRIER();
    }
    { // ph1: (rh1, kh0) — A-q1/q3 now guaranteed
      PH_READS(1, 0, 0)
      async_copy16(gB0 + kk, lBn + dB0);
      async_copy16(gB1 + kk, lBn + dB0 + 8 * 64);
      BARRIER();
      PH_MFMA(1)
      BARRIER();
    }
    { // ph2: (rh0, kh1)
      PH_READS(0, 1, 1)
      async_copy16(gB2 + kk, lBn + dB0 + 16 * 64);
      async_copy16(gB3 + kk, lBn + dB0 + 24 * 64);
      BARRIER();
      PH_MFMA(0)
      BARRIER();
    }
    { // ph3: (rh1, kh1) — issue late loads last; land t+1's early set
      PH_READS(1, 1, 0)
      async_copy16(gAq1 + kk, lAn + dAq1);
      async_copy16(gAq3 + kk, lAn + dAq3);
      BARRIER();
      PH_MFMA(1)
      WAITV(2);        // lands the 6 early loads of tile t+1; 2 late stay in flight
      BARRIER();
    }
  }

  // peeled last tile: no prefetch; one vmcnt(0) to land its late A-quarters
  {
    const unsigned short* lAc = &lA[(NT - 1) & 1][0];
    const unsigned short* lBc = &lB[(NT - 1) & 1][0];
    bf16x8 bf[2][2];
    { PH_READS(0, 0, 1) BARRIER(); PH_MFMA(0) WAITV(0); BARRIER(); }
    { PH_READS(1, 0, 0) BARRIER(); PH_MFMA(1) BARRIER(); }
    { PH_READS(0, 1, 1) BARRIER(); PH_MFMA(0) BARRIER(); }
    { PH_READS(1, 1, 0) BARRIER(); PH_MFMA(1) BARRIER(); }
  }
#undef PH_READS
#undef PH_MFMA

  // C/D layout: col = lane&31, row = (reg&3) + 8*(reg>>2) + 4*(lane>>5)
  const int rbase = 4 * khi;
  const long crow0 = m0 + wrh * 128;
  const long ccol0 = n0 + wcn * 64;
  if (OUTBF16) {
    unsigned short* C = (unsigned short*)(blockIdx.z ? Cout2 : Cout);
#pragma unroll
    for (int ig = 0; ig < 4; ++ig)
#pragma unroll
      for (int j = 0; j < 2; ++j) {
        long col = ccol0 + j * 32 + l31;
#pragma unroll
        for (int reg = 0; reg < 16; ++reg) {
          long row = crow0 + ig * 32 + (reg & 3) + 8 * (reg >> 2) + rbase;
          C[row * (long)ldc + col] = f2bf(acc[ig][j][reg]);
        }
      }
  } else {
    float* C = (float*)(blockIdx.z ? Cout2 : Cout);
#pragma unroll
    for (int ig = 0; ig < 4; ++ig)
#pragma unroll
      for (int j = 0; j < 2; ++j) {
        long col = ccol0 + j * 32 + l31;
#pragma unroll
        for (int reg = 0; reg < 16; ++reg) {
          long row = crow0 + ig * 32 + (reg & 3) + 8 * (reg >> 2) + rbase;
          C[row * (long)ldc + col] = acc[ig][j][reg];
        }
      }
  }

  if (STATS) {
    // per-column sum/sumsq over the block's 256 rows -> P[n0..+255], P[2048+n0..]
    float* sred = (float*)&lA[0][0];   // 512 floats; last tile read lA[1] (NT even)
    sred[tid] = 0.f;                   // sum[0..255] | sumsq[256..511]
    __syncthreads();
#pragma unroll
    for (int j = 0; j < 2; ++j) {
      float s = 0.f, s2 = 0.f;
#pragma unroll
      for (int ig = 0; ig < 4; ++ig)
#pragma unroll
        for (int reg = 0; reg < 16; ++reg) {
          float v = acc[ig][j][reg];
          s += v;
          s2 = fmaf(v, v, s2);
        }
      int cl = wcn * 64 + j * 32 + l31;      // 0..255
      atomicAdd(&sred[cl], s);
      atomicAdd(&sred[256 + cl], s2);
    }
    __syncthreads();
    if (tid < 256) atomicAdd(&P[n0 + tid], sred[tid]);
    else           atomicAdd(&P[2048 + n0 + tid - 256], sred[tid]);
  }
}

// ------- fused BN-finalize (per-block LDS table) + BN-apply + relu + row-norm +
// hyperbolic factor. Per-block preamble: 256 threads x 8 cols compute
// a = g*rsqrt(var+eps), sh = be - mean*a into 16 KiB LDS (same op order as the
// verified k_bnfin -> bit-identical; this exact body passed in the r15 mega run).
// Removes the separate k_bnfin launch (9 -> 7 graph nodes).
template <bool STAGE2>
__global__ void __launch_bounds__(256) k_fuse(const unsigned short* __restrict__ Zb,
                                              const float* __restrict__ P,
                                              const float* __restrict__ g,
                                              const float* __restrict__ be,
                                              unsigned short* __restrict__ Ab) {
  __shared__ float scsh[4096];                    // sc[2048] | sh[2048]
  const int t = threadIdx.x, wave = t >> 6, lane = t & 63;
  const long row = (long)blockIdx.x * 4 + wave;

#pragma unroll
  for (int c = 0; c < 2; ++c) {
    int i4 = t * 2 + c;                           // float4 index 0..511
    float4 s = ((const float4*)P)[i4];
    float4 q = ((const float4*)P)[512 + i4];
    float4 gg = ((const float4*)g)[i4];
    float4 bb = ((const float4*)be)[i4];
    float sm[4] = {s.x, s.y, s.z, s.w}, sq[4] = {q.x, q.y, q.z, q.w};
    float gv[4] = {gg.x, gg.y, gg.z, gg.w}, bv[4] = {bb.x, bb.y, bb.z, bb.w};
#pragma unroll
    for (int k = 0; k < 4; ++k) {
      float mean = sm[k] * (1.f / 8192.f);
      float var = sq[k] * (1.f / 8192.f) - mean * mean;
      float a = gv[k] * rsqrtf(var + 1e-5f);
      scsh[i4 * 4 + k] = a;
      scsh[2048 + i4 * 4 + k] = bv[k] - mean * a;
    }
  }
  __syncthreads();

  float sc[32], sh[32];
#pragma unroll
  for (int c = 0; c < 4; ++c) {
    int cb = (lane + 64 * c) * 8;
    float4 a0 = *(const float4*)&scsh[cb],        a1 = *(const float4*)&scsh[cb + 4];
    float4 h0 = *(const float4*)&scsh[2048 + cb], h1 = *(const float4*)&scsh[2048 + cb + 4];
    sc[c * 8 + 0] = a0.x; sc[c * 8 + 1] = a0.y; sc[c * 8 + 2] = a0.z; sc[c * 8 + 3] = a0.w;
    sc[c * 8 + 4] = a1.x; sc[c * 8 + 5] = a1.y; sc[c * 8 + 6] = a1.z; sc[c * 8 + 7] = a1.w;
    sh[c * 8 + 0] = h0.x; sh[c * 8 + 1] = h0.y; sh[c * 8 + 2] = h0.z; sh[c * 8 + 3] = h0.w;
    sh[c * 8 + 4] = h1.x; sh[c * 8 + 5] = h1.y; sh[c * 8 + 6] = h1.z; sh[c * 8 + 7] = h1.w;
  }

  const us8* zr = (const us8*)(Zb + row * 2048);
  float v[32];
  float ss = 0.f;
#pragma unroll
  for (int c = 0; c < 4; ++c) {
    us8 z8 = zr[lane + 64 * c];
#pragma unroll
    for (int j = 0; j < 8; ++j) {
      float xv = fmaxf(fmaf(bf2f(z8[j]), sc[c * 8 + j], sh[c * 8 + j]), 0.f);
      v[c * 8 + j] = xv;
      ss = fmaf(xv, xv, ss);
    }
  }
#pragma unroll
  for (int o = 32; o > 0; o >>= 1) ss += __shfl_xor(ss, o, 64);
  float n2 = ss;

  const float rsc = 0.31622776601683794f;  // sqrt(0.1)
  float fac;
  if (STAGE2) {
    float nn = sqrtf(n2);
    float vn = fmaxf(nn, 1e-8f);
    float tt = rsc * vn;
    float scl = tanhf(tt) / tt;
    float hn = scl * nn;
    float cn = fminf(fmaxf(hn, 1e-8f), 1.0f);
    float z = rsc * cn;
    fac = scl * (atanhf(z) / z);
  } else {
    fac = 0.f;
    if (n2 > 0.f) {
      float n = sqrtf(n2);
      float th = tanhf(rsc * n);
      float s = 0.9f * th / (rsc * n);
      float dn = fmaxf(s * n, 1e-8f);
      float z = rsc * dn;
      fac = -(atanhf(z) / z) * s;
    }
  }
  us8* dr = (us8*)(Ab + row * 2048);
#pragma unroll
  for (int c = 0; c < 4; ++c) {
    us8 o8;
#pragma unroll
    for (int j = 0; j < 8; ++j) o8[j] = f2bf(v[c * 8 + j] * fac);
    dr[lane + 64 * c] = o8;
  }
}

// ---- log_softmax over 1000 cols; one wave per row; vectorized us8/float4 path ----
// lane owns 8 consecutive cols per chunk: chunk0 = lane*8 (0..511, all lanes full),
// chunk1 = 512+lane*8 (512..999: lanes 0..60 full, 61..63 empty) -> no partial
// vectors at all. Za/Zb2 cols 1000..1023 are never read (padded W3 rows).
__global__ void __launch_bounds__(256) k_lsm(const unsigned short* __restrict__ Za,
                                             const unsigned short* __restrict__ Zb2,
                                             const float* __restrict__ b3,
                                             float* __restrict__ out) {
  const int t = threadIdx.x, wave = t >> 6, lane = t & 63;
  const long row = (long)blockIdx.x * 4 + wave;
  const us8* za8 = (const us8*)(Za + row * 1024);
  const us8* zb8 = (const us8*)(Zb2 + row * 1024);

  float v[16];
  float mx = -3.4e38f;
#pragma unroll
  for (int c = 0; c < 2; ++c) {
    const bool ok = (c == 0) | (lane < 61);
    if (ok) {
      us8 a8 = za8[c * 64 + lane];
      us8 b8 = zb8[c * 64 + lane];
      const float* bp = b3 + c * 512 + lane * 8;
      float4 bA = *(const float4*)bp;
      float4 bB = *(const float4*)(bp + 4);
      float bb[8] = {bA.x, bA.y, bA.z, bA.w, bB.x, bB.y, bB.z, bB.w};
#pragma unroll
      for (int j = 0; j < 8; ++j) {
        float x = bf2f(a8[j]) + bf2f(b8[j]) + bb[j];
        v[c * 8 + j] = x;
        mx = fmaxf(mx, x);
      }
    } else {
#pragma unroll
      for (int j = 0; j < 8; ++j) v[c * 8 + j] = -3.4e38f;
    }
  }
#pragma unroll
  for (int o = 32; o > 0; o >>= 1) mx = fmaxf(mx, __shfl_xor(mx, o, 64));

  float se = 0.f;
#pragma unroll
  for (int c = 0; c < 2; ++c)
#pragma unroll
    for (int j = 0; j < 8; ++j)
      if ((c == 0) | (lane < 61)) se += expf(v[c * 8 + j] - mx);
#pragma unroll
  for (int o = 32; o > 0; o >>= 1) se += __shfl_xor(se, o, 64);
  float mls = mx + logf(se);

  float* orow = out + row * 1000;
#pragma unroll
  for (int c = 0; c < 2; ++c) {
    if ((c == 0) | (lane < 61)) {
      float4 o0 = {v[c * 8 + 0] - mls, v[c * 8 + 1] - mls, v[c * 8 + 2] - mls, v[c * 8 + 3] - mls};
      float4 o1 = {v[c * 8 + 4] - mls, v[c * 8 + 5] - mls, v[c * 8 + 6] - mls, v[c * 8 + 7] - mls};
      float* op = orow + c * 512 + lane * 8;
      *(float4*)op = o0;
      *(float4*)(op + 4) = o1;
    }
  }
}

extern "C" void kernel_launch(void* const* d_in, const int* in_sizes, int n_in,
                              void* d_out, int out_size, void* d_ws, size_t ws_size,
                              hipStream_t stream) {
  (void)in_sizes; (void)n_in; (void)out_size; (void)ws_size;
  const float* x   = (const float*)d_in[0];
  const float* W1  = (const float*)d_in[1];
  // d_in[2] = b1: exactly cancelled by BN (mean absorbs it)
  const float* g1  = (const float*)d_in[3];
  const float* be1 = (const float*)d_in[4];
  const float* W2  = (const float*)d_in[5];
  // d_in[6] = b2: cancelled by BN
  const float* g2  = (const float*)d_in[7];
  const float* be2 = (const float*)d_in[8];
  const float* W3  = (const float*)d_in[9];
  const float* b3  = (const float*)d_in[10];
  float* out = (float*)d_out;

  char* ws = (char*)d_ws;
  size_t off = 0;
  auto alloc = [&](size_t bytes) {
    void* p = ws + off;
    off += (bytes + 255) & ~(size_t)255;
    return p;
  };
  unsigned short* Xb  = (unsigned short*)alloc((size_t)8192 * 1024 * 2);
  unsigned short* W1b = (unsigned short*)alloc((size_t)2048 * 1024 * 2);
  unsigned short* W2b = (unsigned short*)alloc((size_t)2048 * 2048 * 2);
  unsigned short* W3b = (unsigned short*)alloc((size_t)1024 * 2048 * 2);
  unsigned short* Zb  = (unsigned short*)alloc((size_t)8192 * 2048 * 2);
  unsigned short* Ab  = (unsigned short*)alloc((size_t)8192 * 2048 * 2);
  unsigned short* Z3a = (unsigned short*)alloc((size_t)8192 * 1024 * 2);
  float* P            = (float*)alloc((size_t)2 * 4096 * 4);   // P1 | P2, zeroed by k_prep
  float* P2 = P + 4096;
  // split-K slice-1 output aliases Zb (dead after k_fuse<true>; 32 MiB >= 16 MiB)
  unsigned short* Z3b = Zb;

  // conversions + P zeroing
  k_prep<<<16392, 256, 0, stream>>>(x, W1, W2, W3, Xb, W1b, W2b, W3b, P);

  // layer 1: GEMM (+BN stats) -> fused BN-finalize+apply+hyperbolic
  k_gemm<true, true><<<dim3(8, 32, 1), 512, 0, stream>>>(Xb, W1b, Zb, Zb, 1024, 1024, 1024, 2048, P);
  k_fuse<false><<<2048, 256, 0, stream>>>(Zb, P, g1, be1, Ab);

  // layer 2
  k_gemm<true, true><<<dim3(8, 32, 1), 512, 0, stream>>>(Ab, W2b, Zb, Zb, 2048, 2048, 2048, 2048, P2);
  k_fuse<true><<<2048, 256, 0, stream>>>(Zb, P2, g2, be2, Ab);

  // layer 3: split-K=2 in ONE launch (blockIdx.z), bf16 partials summed in k_lsm
  k_gemm<true, false><<<dim3(4, 32, 2), 512, 0, stream>>>(Ab, W3b, Z3a, Z3b, 1024, 2048, 2048, 1024, nullptr);
  k_lsm<<<2048, 256, 0, stream>>>(Z3a, Z3b, b3, out);
}